// Round 3
// baseline (1229.149 us; speedup 1.0000x reference)
//
#include <hip/hip_runtime.h>

#define N_NODES 81920
#define N_EDGES 1310720
#define NG 256
#define D 64
#define TM 64
#define SA 65   // LDS row stride: spreads banks, worst 4-way alias on pair-adds (cheap)

__device__ __forceinline__ unsigned bf16rne(float f) {
    unsigned u = __float_as_uint(f);
    return (u + 0x7fffu + ((u >> 16) & 1u)) >> 16;
}

// ---------------- CSR build ----------------

__global__ void zero_ints(int* __restrict__ p, int n) {
    int i = blockIdx.x * blockDim.x + threadIdx.x;
    if (i < n) p[i] = 0;
}

__global__ void count_deg(const int* __restrict__ dst, int* __restrict__ cnt) {
    int e = blockIdx.x * blockDim.x + threadIdx.x;
    if (e < N_EDGES) atomicAdd(&cnt[dst[e]], 1);
}

__global__ void scan_block(const int* __restrict__ cnt, int* __restrict__ row_ptr,
                           int* __restrict__ bsums) {
    __shared__ int s[256];
    int tid = threadIdx.x;
    int i = blockIdx.x * 256 + tid;
    int v = cnt[i];
    s[tid] = v;
    __syncthreads();
    for (int ofs = 1; ofs < 256; ofs <<= 1) {
        int t = (tid >= ofs) ? s[tid - ofs] : 0;
        __syncthreads();
        s[tid] += t;
        __syncthreads();
    }
    row_ptr[i] = s[tid] - v;               // exclusive
    if (tid == 255) bsums[blockIdx.x] = s[255];
}

__global__ void scan_top(int* __restrict__ bsums) {   // 320 entries, 1 block x 512
    __shared__ int s[512];
    int tid = threadIdx.x;
    int v = (tid < 320) ? bsums[tid] : 0;
    s[tid] = v;
    __syncthreads();
    for (int ofs = 1; ofs < 512; ofs <<= 1) {
        int t = (tid >= ofs) ? s[tid - ofs] : 0;
        __syncthreads();
        s[tid] += t;
        __syncthreads();
    }
    if (tid < 320) bsums[tid] = s[tid] - v; // exclusive
}

__global__ void add_offsets(int* __restrict__ row_ptr, const int* __restrict__ bsums) {
    int i = blockIdx.x * 256 + threadIdx.x;
    row_ptr[i] += bsums[blockIdx.x];
    if (i == 0) row_ptr[N_NODES] = N_EDGES;
}

// pack (src, dst%64) into one int: src < 2^17, 6 bits for dst-in-block
__global__ void bucket(const int* __restrict__ src, const int* __restrict__ dst,
                       const int* __restrict__ row_ptr, int* __restrict__ cur,
                       int* __restrict__ esp) {
    int e = blockIdx.x * blockDim.x + threadIdx.x;
    if (e < N_EDGES) {
        int d = dst[e];
        int ofs = atomicAdd(&cur[d], 1);
        esp[row_ptr[d] + ofs] = (src[e] << 6) | (d & 63);
    }
}

__global__ void find_first(const int* __restrict__ batch, int* __restrict__ fidx) {
    int i = blockIdx.x * blockDim.x + threadIdx.x;
    if (i < N_NODES) {
        int b = batch[i];
        if (i == 0 || batch[i - 1] != b) fidx[b] = i;
    }
}

__global__ void to_bf16(const float* __restrict__ src, unsigned* __restrict__ dstb, int npairs) {
    int i = blockIdx.x * blockDim.x + threadIdx.x;
    if (i < npairs) {
        float a = src[2 * i], b = src[2 * i + 1];
        dstb[i] = bf16rne(a) | (bf16rne(b) << 16);
    }
}

// ---------------- fused SAGE layer: bf16 gather + LDS-atomic aggregate + fp32 dual GEMM ----

__global__ __launch_bounds__(256, 4) void sage_layer(
    const float* __restrict__ hin,          // fp32 [N][64], self features + GEMM
    const unsigned* __restrict__ hbin,      // bf16x2 [N][32], gather source
    float* __restrict__ hout,               // fp32 out
    unsigned* __restrict__ hboutb,          // bf16x2 out (may be null)
    const int* __restrict__ row_ptr, const int* __restrict__ esp,
    const float* __restrict__ Wl, const float* __restrict__ bl,
    const float* __restrict__ Wr, int relu)
{
    __shared__ float As[TM * SA];     // mean-aggregated neighbors, [m][k]
    __shared__ float Xs[TM * SA];     // self features
    __shared__ float invs[TM];

    const int tid  = threadIdx.x;
    const int base = blockIdx.x * TM;
    const int lane = tid & 63;
    const int w    = tid >> 6;
    const int l5   = lane & 31;
    const int hi   = lane >> 5;       // 0 = edge 2u, 1 = edge 2u+1

    if (tid < TM) {
        int deg = row_ptr[base + tid + 1] - row_ptr[base + tid];
        invs[tid] = 1.0f / (float)max(deg, 1);
    }
    for (int idx = tid; idx < TM * D; idx += 256) {
        int m = idx >> 6, k = idx & 63;
        Xs[m * SA + k] = hin[(base << 6) + idx];
        As[m * SA + k] = 0.0f;
    }
    __syncthreads();

    // aggregation: contiguous chunk per wave; 64 edge-ids loaded per wave-instr,
    // 2 edges gathered per wave-instr (half-wave each, bf16x2/lane = 128B row)
    const int e0    = row_ptr[base];
    const int e1    = row_ptr[base + TM];
    const int chunk = ((e1 - e0) + 3) >> 2;
    int e = e0 + w * chunk;
    const int ee = min(e + chunk, e1);

    for (; e + 64 <= ee; e += 64) {
        int pv = __builtin_nontemporal_load(&esp[e + lane]);   // 64 edges, coalesced
        #pragma unroll
        for (int g = 0; g < 4; ++g) {
            int pp[8];
            unsigned wb[8];
            #pragma unroll
            for (int u = 0; u < 8; ++u)
                pp[u] = __shfl(pv, ((g * 8 + u) << 1) + hi);
            #pragma unroll
            for (int u = 0; u < 8; ++u)
                wb[u] = __builtin_nontemporal_load(&hbin[(pp[u] >> 6) * 32 + l5]);
            #pragma unroll
            for (int u = 0; u < 8; ++u) {
                float fx = __uint_as_float(wb[u] << 16);          // feature 2*l5
                float fy = __uint_as_float(wb[u] & 0xffff0000u);  // feature 2*l5+1
                int ra = (pp[u] & 63) * SA + (l5 << 1);
                atomicAdd(&As[ra],     fx);
                atomicAdd(&As[ra + 1], fy);
            }
        }
    }
    for (; e < ee; ++e) {                       // tail, < 64 edges per wave
        int p = esp[e];
        unsigned wb = hbin[(p >> 6) * 32 + l5];
        if (!hi) {
            float fx = __uint_as_float(wb << 16);
            float fy = __uint_as_float(wb & 0xffff0000u);
            int ra = (p & 63) * SA + (l5 << 1);
            atomicAdd(&As[ra],     fx);
            atomicAdd(&As[ra + 1], fy);
        }
    }
    __syncthreads();

    for (int idx = tid; idx < TM * D; idx += 256) {
        int m = idx >> 6, k = idx & 63;
        As[m * SA + k] *= invs[m];
    }
    __syncthreads();

    // GEMM: out[m][j] = sum_k As[m][k]*Wl[k][j] + Xs[m][k]*Wr[k][j] + bl[j]
    const int j0 = (tid & 15) << 2;
    const int m0 = (tid >> 4) << 2;
    float o[4][4];
    float4 b4 = *(const float4*)&bl[j0];
    #pragma unroll
    for (int mi = 0; mi < 4; ++mi) {
        o[mi][0] = b4.x; o[mi][1] = b4.y; o[mi][2] = b4.z; o[mi][3] = b4.w;
    }

    #pragma unroll 8
    for (int k = 0; k < D; ++k) {
        float4 wl = *(const float4*)&Wl[(k << 6) + j0];   // global, L1-resident broadcast
        float4 wr = *(const float4*)&Wr[(k << 6) + j0];
        #pragma unroll
        for (int mi = 0; mi < 4; ++mi) {
            float a = As[(m0 + mi) * SA + k];
            float x = Xs[(m0 + mi) * SA + k];
            o[mi][0] += a * wl.x + x * wr.x;
            o[mi][1] += a * wl.y + x * wr.y;
            o[mi][2] += a * wl.z + x * wr.z;
            o[mi][3] += a * wl.w + x * wr.w;
        }
    }

    #pragma unroll
    for (int mi = 0; mi < 4; ++mi) {
        float4 r = make_float4(o[mi][0], o[mi][1], o[mi][2], o[mi][3]);
        if (relu) {
            r.x = fmaxf(r.x, 0.f); r.y = fmaxf(r.y, 0.f);
            r.z = fmaxf(r.z, 0.f); r.w = fmaxf(r.w, 0.f);
        }
        *(float4*)&hout[(base + m0 + mi) * D + j0] = r;
        if (hboutb) {
            unsigned p0 = bf16rne(r.x) | (bf16rne(r.y) << 16);
            unsigned p1 = bf16rne(r.z) | (bf16rne(r.w) << 16);
            unsigned* dp = &hboutb[(base + m0 + mi) * 32 + (j0 >> 1)];
            dp[0] = p0; dp[1] = p1;
        }
    }
}

// ---------------- final layer: only the 256 output nodes ----------------

__global__ void final_agg(const float* __restrict__ hin, const int* __restrict__ row_ptr,
                          const int* __restrict__ esp, const int* __restrict__ fidx,
                          float* __restrict__ aggF, float* __restrict__ xF)
{
    int gw   = (blockIdx.x * blockDim.x + threadIdx.x) >> 6;  // one wave per output node
    int lane = threadIdx.x & 63;
    if (gw >= NG) return;
    int node = fidx[gw];
    int s = row_ptr[node];
    int epd = row_ptr[node + 1];
    float acc = 0.f;
    int e = s;
    for (; e + 8 <= epd; e += 8) {
        int p[8];
        float v[8];
        #pragma unroll
        for (int u = 0; u < 8; ++u) p[u] = esp[e + u];
        #pragma unroll
        for (int u = 0; u < 8; ++u) v[u] = hin[(p[u] >> 6) * D + lane];
        #pragma unroll
        for (int u = 0; u < 8; ++u) acc += v[u];
    }
    for (; e < epd; ++e) acc += hin[(esp[e] >> 6) * D + lane];
    acc *= 1.0f / (float)max(epd - s, 1);
    aggF[gw * D + lane] = acc;
    xF[gw * D + lane]   = hin[node * D + lane];
}

__global__ __launch_bounds__(256, 3) void final_gemm(
    const float* __restrict__ aggF, const float* __restrict__ xF,
    const float* __restrict__ Wl, const float* __restrict__ bl,
    const float* __restrict__ Wr, float* __restrict__ out)
{
    __shared__ float As[TM * SA];
    __shared__ float Xs[TM * SA];

    const int tid  = threadIdx.x;
    const int base = blockIdx.x * TM;

    for (int idx = tid; idx < TM * D; idx += 256) {
        int m = idx >> 6, k = idx & 63;
        As[m * SA + k] = aggF[(base << 6) + idx];
        Xs[m * SA + k] = xF[(base << 6) + idx];
    }
    __syncthreads();

    const int j0 = (tid & 15) << 2;
    const int m0 = (tid >> 4) << 2;
    float o[4][4];
    float4 b4 = *(const float4*)&bl[j0];
    #pragma unroll
    for (int mi = 0; mi < 4; ++mi) {
        o[mi][0] = b4.x; o[mi][1] = b4.y; o[mi][2] = b4.z; o[mi][3] = b4.w;
    }
    #pragma unroll 8
    for (int k = 0; k < D; ++k) {
        float4 wl = *(const float4*)&Wl[(k << 6) + j0];
        float4 wr = *(const float4*)&Wr[(k << 6) + j0];
        #pragma unroll
        for (int mi = 0; mi < 4; ++mi) {
            float a = As[(m0 + mi) * SA + k];
            float x = Xs[(m0 + mi) * SA + k];
            o[mi][0] += a * wl.x + x * wr.x;
            o[mi][1] += a * wl.y + x * wr.y;
            o[mi][2] += a * wl.z + x * wr.z;
            o[mi][3] += a * wl.w + x * wr.w;
        }
    }
    #pragma unroll
    for (int mi = 0; mi < 4; ++mi) {
        float4 r = make_float4(o[mi][0], o[mi][1], o[mi][2], o[mi][3]);
        *(float4*)&out[(base + m0 + mi) * D + j0] = r;
    }
}

// ---------------- launch ----------------

extern "C" void kernel_launch(void* const* d_in, const int* in_sizes, int n_in,
                              void* d_out, int out_size, void* d_ws, size_t ws_size,
                              hipStream_t stream)
{
    const float* x     = (const float*)d_in[0];
    const int*   ei    = (const int*)d_in[1];
    const int*   batch = (const int*)d_in[2];
    const float* Wl0 = (const float*)d_in[3];
    const float* bl0 = (const float*)d_in[4];
    const float* Wr0 = (const float*)d_in[5];
    const float* Wl1 = (const float*)d_in[6];
    const float* bl1 = (const float*)d_in[7];
    const float* Wr1 = (const float*)d_in[8];
    const float* Wl2 = (const float*)d_in[9];
    const float* bl2 = (const float*)d_in[10];
    const float* Wr2 = (const float*)d_in[11];
    float* out = (float*)d_out;

    const int* src = ei;             // edge_index[0]
    const int* dst = ei + N_EDGES;   // edge_index[1]

    char* ws = (char*)d_ws;
    size_t off = 0;
    auto alloc = [&](size_t bytes) -> void* {
        void* p = ws + off;
        off = (off + bytes + 255) & ~(size_t)255;
        return p;
    };
    int*      row_ptr = (int*)alloc((N_NODES + 1) * sizeof(int));
    int*      cnt     = (int*)alloc(N_NODES * sizeof(int));       // reused as cursor
    int*      bsums   = (int*)alloc(512 * sizeof(int));
    int*      fidx    = (int*)alloc(NG * sizeof(int));
    float*    aggF    = (float*)alloc((size_t)NG * D * sizeof(float));
    float*    xF      = (float*)alloc((size_t)NG * D * sizeof(float));
    int*      esp     = (int*)alloc((size_t)N_EDGES * sizeof(int));
    float*    h1      = (float*)alloc((size_t)N_NODES * D * sizeof(float));
    float*    h2      = (float*)alloc((size_t)N_NODES * D * sizeof(float));
    unsigned* xb      = (unsigned*)alloc((size_t)N_NODES * 32 * sizeof(unsigned));
    unsigned* h1b     = (unsigned*)alloc((size_t)N_NODES * 32 * sizeof(unsigned));
    (void)ws_size; (void)in_sizes; (void)n_in; (void)out_size;

    zero_ints <<<(N_NODES + 255) / 256, 256, 0, stream>>>(cnt, N_NODES);
    count_deg <<<(N_EDGES + 255) / 256, 256, 0, stream>>>(dst, cnt);
    scan_block<<<320, 256, 0, stream>>>(cnt, row_ptr, bsums);
    scan_top  <<<1, 512, 0, stream>>>(bsums);
    add_offsets<<<320, 256, 0, stream>>>(row_ptr, bsums);
    zero_ints <<<(N_NODES + 255) / 256, 256, 0, stream>>>(cnt, N_NODES);
    bucket    <<<(N_EDGES + 255) / 256, 256, 0, stream>>>(src, dst, row_ptr, cnt, esp);
    find_first<<<320, 256, 0, stream>>>(batch, fidx);
    to_bf16   <<<(N_NODES * 32 + 255) / 256, 256, 0, stream>>>(x, xb, N_NODES * 32);

    sage_layer<<<N_NODES / TM, 256, 0, stream>>>(x,  xb,  h1, h1b, row_ptr, esp, Wl0, bl0, Wr0, 1);
    sage_layer<<<N_NODES / TM, 256, 0, stream>>>(h1, h1b, h2, (unsigned*)nullptr,
                                                 row_ptr, esp, Wl1, bl1, Wr1, 1);

    final_agg <<<NG / 4, 256, 0, stream>>>(h2, row_ptr, esp, fidx, aggF, xF);
    final_gemm<<<NG / TM, 256, 0, stream>>>(aggF, xF, Wl2, bl2, Wr2, out);
}